// Round 3
// baseline (327.828 us; speedup 1.0000x reference)
//
#include <hip/hip_runtime.h>

typedef __attribute__((ext_vector_type(8))) short bf16x8;
typedef __attribute__((ext_vector_type(4))) float f32x4;
typedef __attribute__((ext_vector_type(8))) unsigned short u16x8;
typedef __attribute__((ext_vector_type(4))) unsigned short u16x4;

#define S_LEN 2048
#define BATCH 2
#define EMB 1024
#define NH 16
#define HDIM 64
#define M_ROWS (S_LEN * BATCH)   // 4096
#define N_QKV (3 * EMB)          // 3072

typedef const __attribute__((address_space(1))) unsigned int* gptr_t;
typedef __attribute__((address_space(3))) unsigned int* lptr_t;

__device__ __forceinline__ unsigned short f2b(float f) {
  union { float f; unsigned u; } v; v.f = f;
  unsigned r = v.u + 0x7fff + ((v.u >> 16) & 1);
  return (unsigned short)(r >> 16);
}

// ---------------- fp32 -> bf16 conversion (memory-bound) ----------------
__global__ __launch_bounds__(256) void cvt_f32_bf16(const float* __restrict__ in,
                                                    unsigned short* __restrict__ out,
                                                    int n4) {
  int i = blockIdx.x * 256 + threadIdx.x;
  if (i >= n4) return;
  float4 a = reinterpret_cast<const float4*>(in)[i];
  u16x4 o;
  o[0] = f2b(a.x); o[1] = f2b(a.y); o[2] = f2b(a.z); o[3] = f2b(a.w);
  reinterpret_cast<u16x4*>(out)[i] = o;
}

// ---------------- bf16 GEMM, C = A(M,K) * B(N,K)^T ----------------
// 128x128 tile, BK=32, 4 waves (2x2), each wave 64x64 out (4x4 frags of 16x16)
// Staging: global_load_lds width=16, linear LDS (m97 structure, 874 TF verified)
template <int OUT_BF16>
__global__ __launch_bounds__(256) void gemm_bt(const unsigned short* __restrict__ A,
                                               const unsigned short* __restrict__ Bm,
                                               void* __restrict__ Cv,
                                               int Md, int Nd, int Kd) {
  __shared__ unsigned short As[128][32];  // linear: global_load_lds needs contiguous dest
  __shared__ unsigned short Bs[128][32];
  int t = threadIdx.x;
  int bm = blockIdx.y, bn = blockIdx.x;
  int wid = t >> 6, lane = t & 63;
  int wr = wid >> 1, wc = wid & 1;
  int fr = lane & 15, fq = lane >> 4;
  int lrow = lane >> 2;          // 0..15: row within 16-row chunk
  int lcol = (lane & 3) * 8;     // element col within 32 (16B granules)

  f32x4 acc[4][4];
#pragma unroll
  for (int i = 0; i < 4; ++i)
#pragma unroll
    for (int j = 0; j < 4; ++j) acc[i][j] = (f32x4){0.f, 0.f, 0.f, 0.f};

  int nkt = Kd >> 5;
  for (int kt = 0; kt < nkt; ++kt) {
    // each wave stages 32 rows of A and 32 rows of B (2 chunks of 16 rows each)
    const unsigned short* ga = A + (size_t)(bm * 128 + wid * 32 + lrow) * Kd + kt * 32 + lcol;
    const unsigned short* gb = Bm + (size_t)(bn * 128 + wid * 32 + lrow) * Kd + kt * 32 + lcol;
#pragma unroll
    for (int j = 0; j < 2; ++j) {
      __builtin_amdgcn_global_load_lds((gptr_t)(ga + (size_t)j * 16 * Kd),
                                       (lptr_t)&As[wid * 32 + j * 16][0], 16, 0, 0);
      __builtin_amdgcn_global_load_lds((gptr_t)(gb + (size_t)j * 16 * Kd),
                                       (lptr_t)&Bs[wid * 32 + j * 16][0], 16, 0, 0);
    }
    __syncthreads();   // drains vmcnt -> LDS tiles complete

    bf16x8 af[4], bfv[4];
#pragma unroll
    for (int mt = 0; mt < 4; ++mt)
      af[mt] = *reinterpret_cast<const bf16x8*>(&As[wr * 64 + mt * 16 + fr][fq * 8]);
#pragma unroll
    for (int nt = 0; nt < 4; ++nt)
      bfv[nt] = *reinterpret_cast<const bf16x8*>(&Bs[wc * 64 + nt * 16 + fr][fq * 8]);
#pragma unroll
    for (int mt = 0; mt < 4; ++mt)
#pragma unroll
      for (int nt = 0; nt < 4; ++nt)
        acc[mt][nt] = __builtin_amdgcn_mfma_f32_16x16x32_bf16(af[mt], bfv[nt], acc[mt][nt], 0, 0, 0);
    __syncthreads();
  }

#pragma unroll
  for (int mt = 0; mt < 4; ++mt)
#pragma unroll
    for (int nt = 0; nt < 4; ++nt)
#pragma unroll
      for (int r = 0; r < 4; ++r) {
        int row = bm * 128 + wr * 64 + mt * 16 + fq * 4 + r;
        int col = bn * 128 + wc * 64 + nt * 16 + fr;
        float val = acc[mt][nt][r];
        if (OUT_BF16)
          reinterpret_cast<unsigned short*>(Cv)[(size_t)row * Nd + col] = f2b(val);
        else
          reinterpret_cast<float*>(Cv)[(size_t)row * Nd + col] = val;
      }
}

// ---------------- flash attention ----------------
// grid: (S/64, B*H); 4 waves, each owns 16 q-rows. KV tiles of 64.
__global__ __launch_bounds__(256) void attn_kernel(const unsigned short* __restrict__ qkv,
                                                   unsigned short* __restrict__ att) {
  __shared__ unsigned short Ks[64][72];      // +8 pad -> 144B stride, 2-way bank
  __shared__ unsigned short Vs[64][72];
  __shared__ unsigned short Ps[4][16][72];   // per-wave P staging
  int t = threadIdx.x;
  int wid = t >> 6, lane = t & 63;
  int fr = lane & 15, fq = lane >> 4;
  int bh = blockIdx.y;
  int b = bh >> 4;   // H = 16
  int h = bh & 15;
  int q0 = blockIdx.x * 64;

  // Q fragments (A operand): lane holds row fr, k = kc*32 + fq*8 + j
  int qi = q0 + wid * 16 + fr;
  const unsigned short* qrow = qkv + ((size_t)qi * BATCH + b) * N_QKV + h * 192;
  bf16x8 qf[2];
  qf[0] = *reinterpret_cast<const bf16x8*>(qrow + fq * 8);
  qf[1] = *reinterpret_cast<const bf16x8*>(qrow + 32 + fq * 8);

  f32x4 o[4];
#pragma unroll
  for (int dt = 0; dt < 4; ++dt) o[dt] = (f32x4){0.f, 0.f, 0.f, 0.f};
  float m_run[4], l_run[4];
#pragma unroll
  for (int r = 0; r < 4; ++r) { m_run[r] = -1e30f; l_run[r] = 0.f; }

  for (int kt = 0; kt < S_LEN / 64; ++kt) {
    // stage K and V tiles (64x64 each)
#pragma unroll
    for (int i = 0; i < 2; ++i) {
      int c = t + i * 256;            // 0..511
      int row = c >> 3, c8 = (c & 7) * 8;
      const unsigned short* kr =
          qkv + ((size_t)(kt * 64 + row) * BATCH + b) * N_QKV + h * 192 + 64;
      *reinterpret_cast<u16x8*>(&Ks[row][c8]) = *reinterpret_cast<const u16x8*>(kr + c8);
      *reinterpret_cast<u16x8*>(&Vs[row][c8]) = *reinterpret_cast<const u16x8*>(kr + 64 + c8);
    }
    __syncthreads();

    // S = Q * K^T  (each wave: 16 x 64)
    f32x4 sf[4];
#pragma unroll
    for (int nt = 0; nt < 4; ++nt) {
      bf16x8 bk0 = *reinterpret_cast<const bf16x8*>(&Ks[nt * 16 + fr][fq * 8]);
      bf16x8 bk1 = *reinterpret_cast<const bf16x8*>(&Ks[nt * 16 + fr][32 + fq * 8]);
      f32x4 s = (f32x4){0.f, 0.f, 0.f, 0.f};
      s = __builtin_amdgcn_mfma_f32_16x16x32_bf16(qf[0], bk0, s, 0, 0, 0);
      s = __builtin_amdgcn_mfma_f32_16x16x32_bf16(qf[1], bk1, s, 0, 0, 0);
      sf[nt] = s;
    }
#pragma unroll
    for (int nt = 0; nt < 4; ++nt) sf[nt] *= 0.125f;  // 1/sqrt(64)

    // online softmax; lane holds rows fq*4+r, col fr + nt*16
    float p[4][4];
#pragma unroll
    for (int r = 0; r < 4; ++r) {
      float mx = fmaxf(fmaxf(sf[0][r], sf[1][r]), fmaxf(sf[2][r], sf[3][r]));
#pragma unroll
      for (int m = 1; m < 16; m <<= 1) mx = fmaxf(mx, __shfl_xor(mx, m));
      float mnew = fmaxf(m_run[r], mx);
      float alpha = __expf(m_run[r] - mnew);
      m_run[r] = mnew;
      float rs = 0.f;
#pragma unroll
      for (int nt = 0; nt < 4; ++nt) {
        float pv = __expf(sf[nt][r] - mnew);
        p[nt][r] = pv;
        rs += pv;
      }
#pragma unroll
      for (int m = 1; m < 16; m <<= 1) rs += __shfl_xor(rs, m);
      l_run[r] = l_run[r] * alpha + rs;
#pragma unroll
      for (int dt = 0; dt < 4; ++dt) o[dt][r] *= alpha;
    }

    // P -> LDS (bf16), reshape C-layout -> A-layout
#pragma unroll
    for (int nt = 0; nt < 4; ++nt)
#pragma unroll
      for (int r = 0; r < 4; ++r)
        Ps[wid][fq * 4 + r][nt * 16 + fr] = f2b(p[nt][r]);

    // O += P * V
#pragma unroll
    for (int kc = 0; kc < 2; ++kc) {
      bf16x8 pa = *reinterpret_cast<const bf16x8*>(&Ps[wid][fr][kc * 32 + fq * 8]);
#pragma unroll
      for (int dt = 0; dt < 4; ++dt) {
        bf16x8 vb;
#pragma unroll
        for (int j = 0; j < 8; ++j) vb[j] = (short)Vs[kc * 32 + fq * 8 + j][dt * 16 + fr];
        o[dt] = __builtin_amdgcn_mfma_f32_16x16x32_bf16(pa, vb, o[dt], 0, 0, 0);
      }
    }
    __syncthreads();
  }

  // epilogue: O /= l, write bf16 to att[(q*B+b)*E + h*64 + d]
#pragma unroll
  for (int dt = 0; dt < 4; ++dt)
#pragma unroll
    for (int r = 0; r < 4; ++r) {
      int q = q0 + wid * 16 + fq * 4 + r;
      int d = dt * 16 + fr;
      float val = o[dt][r] / l_run[r];
      att[((size_t)q * BATCH + b) * EMB + h * 64 + d] = f2b(val);
    }
}

extern "C" void kernel_launch(void* const* d_in, const int* in_sizes, int n_in,
                              void* d_out, int out_size, void* d_ws, size_t ws_size,
                              hipStream_t stream) {
  const float* q_in  = (const float*)d_in[0];
  const float* w_in  = (const float*)d_in[3];
  const float* w_out = (const float*)d_in[4];
  float* out = (float*)d_out;

  unsigned short* ws  = (unsigned short*)d_ws;
  unsigned short* Xb  = ws;                                  // 4096x1024
  unsigned short* Wb  = Xb + (size_t)M_ROWS * EMB;           // 3072x1024
  unsigned short* Ob  = Wb + (size_t)N_QKV * EMB;            // 1024x1024
  unsigned short* QKV = Ob + (size_t)EMB * EMB;              // 4096x3072
  unsigned short* ATT = QKV + (size_t)M_ROWS * N_QKV;        // 4096x1024

  cvt_f32_bf16<<<(M_ROWS * EMB / 4 + 255) / 256, 256, 0, stream>>>(q_in, Xb, M_ROWS * EMB / 4);
  cvt_f32_bf16<<<(N_QKV * EMB / 4 + 255) / 256, 256, 0, stream>>>(w_in, Wb, N_QKV * EMB / 4);
  cvt_f32_bf16<<<(EMB * EMB / 4 + 255) / 256, 256, 0, stream>>>(w_out, Ob, EMB * EMB / 4);

  gemm_bt<1><<<dim3(N_QKV / 128, M_ROWS / 128), 256, 0, stream>>>(Xb, Wb, QKV, M_ROWS, N_QKV, EMB);
  attn_kernel<<<dim3(S_LEN / 64, BATCH * NH), 256, 0, stream>>>(QKV, ATT);
  gemm_bt<0><<<dim3(EMB / 128, M_ROWS / 128), 256, 0, stream>>>(ATT, Ob, out, M_ROWS, EMB, EMB);
}

// Round 4
// 290.869 us; speedup vs baseline: 1.1271x; 1.1271x over previous
//
#include <hip/hip_runtime.h>

typedef __attribute__((ext_vector_type(8))) short bf16x8;
typedef __attribute__((ext_vector_type(4))) float f32x4;
typedef __attribute__((ext_vector_type(8))) unsigned short u16x8;
typedef __attribute__((ext_vector_type(4))) unsigned short u16x4;

#define S_LEN 2048
#define BATCH 2
#define EMB 1024
#define NH 16
#define HDIM 64
#define M_ROWS (S_LEN * BATCH)   // 4096
#define N_QKV (3 * EMB)          // 3072

typedef const __attribute__((address_space(1))) unsigned int* gptr_t;
typedef __attribute__((address_space(3))) unsigned int* lptr_t;

__device__ __forceinline__ unsigned short f2b(float f) {
  union { float f; unsigned u; } v; v.f = f;
  unsigned r = v.u + 0x7fff + ((v.u >> 16) & 1);
  return (unsigned short)(r >> 16);
}

// ---------------- fp32 -> bf16 conversion (memory-bound) ----------------
__global__ __launch_bounds__(256) void cvt_f32_bf16(const float* __restrict__ in,
                                                    unsigned short* __restrict__ out,
                                                    int n4) {
  int i = blockIdx.x * 256 + threadIdx.x;
  if (i >= n4) return;
  float4 a = reinterpret_cast<const float4*>(in)[i];
  u16x4 o;
  o[0] = f2b(a.x); o[1] = f2b(a.y); o[2] = f2b(a.z); o[3] = f2b(a.w);
  reinterpret_cast<u16x4*>(out)[i] = o;
}

// ---------------- bf16 GEMM, C = A(M,K) * B(N,K)^T ----------------
// 128x128 tile, BK=32, 4 waves (2x2), each wave 64x64 out (4x4 frags of 16x16)
// Staging: global_load_lds width=16, linear LDS (m97 structure)
template <int OUT_BF16>
__global__ __launch_bounds__(256) void gemm_bt(const unsigned short* __restrict__ A,
                                               const unsigned short* __restrict__ Bm,
                                               void* __restrict__ Cv,
                                               int Md, int Nd, int Kd) {
  __shared__ unsigned short As[128][32];  // linear: global_load_lds needs contiguous dest
  __shared__ unsigned short Bs[128][32];
  int t = threadIdx.x;
  int bm = blockIdx.y, bn = blockIdx.x;
  int wid = t >> 6, lane = t & 63;
  int wr = wid >> 1, wc = wid & 1;
  int fr = lane & 15, fq = lane >> 4;
  int lrow = lane >> 2;          // 0..15: row within 16-row chunk
  int lcol = (lane & 3) * 8;     // element col within 32 (16B granules)

  f32x4 acc[4][4];
#pragma unroll
  for (int i = 0; i < 4; ++i)
#pragma unroll
    for (int j = 0; j < 4; ++j) acc[i][j] = (f32x4){0.f, 0.f, 0.f, 0.f};

  int nkt = Kd >> 5;
  for (int kt = 0; kt < nkt; ++kt) {
    // each wave stages 32 rows of A and 32 rows of B (2 chunks of 16 rows each)
    const unsigned short* ga = A + (size_t)(bm * 128 + wid * 32 + lrow) * Kd + kt * 32 + lcol;
    const unsigned short* gb = Bm + (size_t)(bn * 128 + wid * 32 + lrow) * Kd + kt * 32 + lcol;
#pragma unroll
    for (int j = 0; j < 2; ++j) {
      __builtin_amdgcn_global_load_lds((gptr_t)(ga + (size_t)j * 16 * Kd),
                                       (lptr_t)&As[wid * 32 + j * 16][0], 16, 0, 0);
      __builtin_amdgcn_global_load_lds((gptr_t)(gb + (size_t)j * 16 * Kd),
                                       (lptr_t)&Bs[wid * 32 + j * 16][0], 16, 0, 0);
    }
    __syncthreads();   // drains vmcnt -> LDS tiles complete

    bf16x8 af[4], bfv[4];
#pragma unroll
    for (int mt = 0; mt < 4; ++mt)
      af[mt] = *reinterpret_cast<const bf16x8*>(&As[wr * 64 + mt * 16 + fr][fq * 8]);
#pragma unroll
    for (int nt = 0; nt < 4; ++nt)
      bfv[nt] = *reinterpret_cast<const bf16x8*>(&Bs[wc * 64 + nt * 16 + fr][fq * 8]);
#pragma unroll
    for (int mt = 0; mt < 4; ++mt)
#pragma unroll
      for (int nt = 0; nt < 4; ++nt)
        acc[mt][nt] = __builtin_amdgcn_mfma_f32_16x16x32_bf16(af[mt], bfv[nt], acc[mt][nt], 0, 0, 0);
    __syncthreads();
  }

#pragma unroll
  for (int mt = 0; mt < 4; ++mt)
#pragma unroll
    for (int nt = 0; nt < 4; ++nt)
#pragma unroll
      for (int r = 0; r < 4; ++r) {
        int row = bm * 128 + wr * 64 + mt * 16 + fq * 4 + r;
        int col = bn * 128 + wc * 64 + nt * 16 + fr;
        float val = acc[mt][nt][r];
        if (OUT_BF16)
          reinterpret_cast<unsigned short*>(Cv)[(size_t)row * Nd + col] = f2b(val);
        else
          reinterpret_cast<float*>(Cv)[(size_t)row * Nd + col] = val;
      }
}

// ---------------- V transpose: qkv -> Vt[b*16+h][d][s] ----------------
// grid (S/64, B*H). LDS tile [64][72] with chunk-XOR swizzle -> 2-way banks.
__global__ __launch_bounds__(256) void vtrans(const unsigned short* __restrict__ qkv,
                                              unsigned short* __restrict__ vt) {
  __shared__ unsigned short Ts[64][72];
  int t = threadIdx.x;
  int kb = blockIdx.x;
  int bh = blockIdx.y;
  int b = bh >> 4, h = bh & 15;
  int k0 = kb * 64;
#pragma unroll
  for (int i = 0; i < 2; ++i) {
    int c = t + i * 256;
    int r = c >> 3, q = c & 7;                 // V row k0+r, d-chunk q
    int chunk = q ^ ((r >> 3) & 7);            // XOR swizzle (read side matches)
    *reinterpret_cast<u16x8*>(&Ts[r][chunk * 8]) =
        *reinterpret_cast<const u16x8*>(
            qkv + ((size_t)(k0 + r) * BATCH + b) * N_QKV + h * 192 + 128 + q * 8);
  }
  __syncthreads();
#pragma unroll
  for (int i = 0; i < 2; ++i) {
    int c = t + i * 256;
    int d = c >> 3, q = c & 7;                 // output row d, k-chunk q
    u16x8 o;
#pragma unroll
    for (int j = 0; j < 8; ++j) {
      int k = q * 8 + j;
      int chunk = (d >> 3) ^ q;                // (k>>3)&7 == q
      o[j] = Ts[k][chunk * 8 + (d & 7)];
    }
    *reinterpret_cast<u16x8*>(&vt[((size_t)bh * 64 + d) * S_LEN + k0 + q * 8]) = o;
  }
}

// ---------------- flash attention ----------------
// grid: (S/64, B*H); 4 waves, each owns 16 q-rows. KV tiles of 64.
// V consumed from pre-transposed Vt -> PV B-fragments are vectorized b128.
__global__ __launch_bounds__(256) void attn_kernel(const unsigned short* __restrict__ qkv,
                                                   const unsigned short* __restrict__ vt,
                                                   unsigned short* __restrict__ att) {
  __shared__ unsigned short Ks[64][72];      // +8 pad -> 144B stride
  __shared__ unsigned short VtS[64][72];     // [d][k] row-major
  __shared__ unsigned short Ps[4][16][72];   // per-wave P staging
  int t = threadIdx.x;
  int wid = t >> 6, lane = t & 63;
  int fr = lane & 15, fq = lane >> 4;
  int bh = blockIdx.y;
  int b = bh >> 4;   // H = 16
  int h = bh & 15;
  int q0 = blockIdx.x * 64;

  // Q fragments (A operand): lane holds row fr, k = kc*32 + fq*8 + j
  int qi = q0 + wid * 16 + fr;
  const unsigned short* qrow = qkv + ((size_t)qi * BATCH + b) * N_QKV + h * 192;
  bf16x8 qf[2];
  qf[0] = *reinterpret_cast<const bf16x8*>(qrow + fq * 8);
  qf[1] = *reinterpret_cast<const bf16x8*>(qrow + 32 + fq * 8);

  f32x4 o[4];
#pragma unroll
  for (int dt = 0; dt < 4; ++dt) o[dt] = (f32x4){0.f, 0.f, 0.f, 0.f};
  float m_run[4], l_run[4];
#pragma unroll
  for (int r = 0; r < 4; ++r) { m_run[r] = -1e30f; l_run[r] = 0.f; }

  for (int kt = 0; kt < S_LEN / 64; ++kt) {
    // stage K tile [k][d] and Vt tile [d][k] (vectorized, coalesced)
#pragma unroll
    for (int i = 0; i < 2; ++i) {
      int c = t + i * 256;            // 0..511
      int row = c >> 3, c8 = (c & 7) * 8;
      *reinterpret_cast<u16x8*>(&Ks[row][c8]) = *reinterpret_cast<const u16x8*>(
          qkv + ((size_t)(kt * 64 + row) * BATCH + b) * N_QKV + h * 192 + 64 + c8);
      *reinterpret_cast<u16x8*>(&VtS[row][c8]) = *reinterpret_cast<const u16x8*>(
          vt + ((size_t)bh * 64 + row) * S_LEN + kt * 64 + c8);
    }
    __syncthreads();

    // S = Q * K^T  (each wave: 16 x 64)
    f32x4 sf[4];
#pragma unroll
    for (int nt = 0; nt < 4; ++nt) {
      bf16x8 bk0 = *reinterpret_cast<const bf16x8*>(&Ks[nt * 16 + fr][fq * 8]);
      bf16x8 bk1 = *reinterpret_cast<const bf16x8*>(&Ks[nt * 16 + fr][32 + fq * 8]);
      f32x4 s = (f32x4){0.f, 0.f, 0.f, 0.f};
      s = __builtin_amdgcn_mfma_f32_16x16x32_bf16(qf[0], bk0, s, 0, 0, 0);
      s = __builtin_amdgcn_mfma_f32_16x16x32_bf16(qf[1], bk1, s, 0, 0, 0);
      sf[nt] = s;
    }
#pragma unroll
    for (int nt = 0; nt < 4; ++nt) sf[nt] *= 0.125f;  // 1/sqrt(64)

    // online softmax; lane holds rows fq*4+r, col fr + nt*16
    float p[4][4];
#pragma unroll
    for (int r = 0; r < 4; ++r) {
      float mx = fmaxf(fmaxf(sf[0][r], sf[1][r]), fmaxf(sf[2][r], sf[3][r]));
#pragma unroll
      for (int m = 1; m < 16; m <<= 1) mx = fmaxf(mx, __shfl_xor(mx, m));
      float mnew = fmaxf(m_run[r], mx);
      float alpha = __expf(m_run[r] - mnew);
      m_run[r] = mnew;
      float rs = 0.f;
#pragma unroll
      for (int nt = 0; nt < 4; ++nt) {
        float pv = __expf(sf[nt][r] - mnew);
        p[nt][r] = pv;
        rs += pv;
      }
#pragma unroll
      for (int m = 1; m < 16; m <<= 1) rs += __shfl_xor(rs, m);
      l_run[r] = l_run[r] * alpha + rs;
#pragma unroll
      for (int dt = 0; dt < 4; ++dt) o[dt][r] *= alpha;
    }

    // P -> LDS (bf16), reshape C-layout -> A-layout
#pragma unroll
    for (int nt = 0; nt < 4; ++nt)
#pragma unroll
      for (int r = 0; r < 4; ++r)
        Ps[wid][fq * 4 + r][nt * 16 + fr] = f2b(p[nt][r]);

    // O += P * V : B-fragment = VtS[d][k] row-major -> vectorized b128
#pragma unroll
    for (int kc = 0; kc < 2; ++kc) {
      bf16x8 pa = *reinterpret_cast<const bf16x8*>(&Ps[wid][fr][kc * 32 + fq * 8]);
#pragma unroll
      for (int dt = 0; dt < 4; ++dt) {
        bf16x8 vb = *reinterpret_cast<const bf16x8*>(&VtS[dt * 16 + fr][kc * 32 + fq * 8]);
        o[dt] = __builtin_amdgcn_mfma_f32_16x16x32_bf16(pa, vb, o[dt], 0, 0, 0);
      }
    }
    __syncthreads();
  }

  // epilogue: O /= l, write bf16 to att[(q*B+b)*E + h*64 + d]
#pragma unroll
  for (int dt = 0; dt < 4; ++dt)
#pragma unroll
    for (int r = 0; r < 4; ++r) {
      int q = q0 + wid * 16 + fq * 4 + r;
      int d = dt * 16 + fr;
      float val = o[dt][r] / l_run[r];
      att[((size_t)q * BATCH + b) * EMB + h * 64 + d] = f2b(val);
    }
}

extern "C" void kernel_launch(void* const* d_in, const int* in_sizes, int n_in,
                              void* d_out, int out_size, void* d_ws, size_t ws_size,
                              hipStream_t stream) {
  const float* q_in  = (const float*)d_in[0];
  const float* w_in  = (const float*)d_in[3];
  const float* w_out = (const float*)d_in[4];
  float* out = (float*)d_out;

  unsigned short* ws  = (unsigned short*)d_ws;
  unsigned short* Xb  = ws;                                  // 4096x1024 (dead after gemm1)
  unsigned short* Wb  = Xb + (size_t)M_ROWS * EMB;           // 3072x1024
  unsigned short* Ob  = Wb + (size_t)N_QKV * EMB;            // 1024x1024
  unsigned short* QKV = Ob + (size_t)EMB * EMB;              // 4096x3072
  unsigned short* ATT = QKV + (size_t)M_ROWS * N_QKV;        // 4096x1024
  unsigned short* Vt  = Xb;                                  // alias: 32*64*2048 == 4096*1024

  cvt_f32_bf16<<<(M_ROWS * EMB / 4 + 255) / 256, 256, 0, stream>>>(q_in, Xb, M_ROWS * EMB / 4);
  cvt_f32_bf16<<<(N_QKV * EMB / 4 + 255) / 256, 256, 0, stream>>>(w_in, Wb, N_QKV * EMB / 4);
  cvt_f32_bf16<<<(EMB * EMB / 4 + 255) / 256, 256, 0, stream>>>(w_out, Ob, EMB * EMB / 4);

  gemm_bt<1><<<dim3(N_QKV / 128, M_ROWS / 128), 256, 0, stream>>>(Xb, Wb, QKV, M_ROWS, N_QKV, EMB);
  vtrans<<<dim3(S_LEN / 64, BATCH * NH), 256, 0, stream>>>(QKV, Vt);
  attn_kernel<<<dim3(S_LEN / 64, BATCH * NH), 256, 0, stream>>>(QKV, Vt, ATT);
  gemm_bt<0><<<dim3(EMB / 128, M_ROWS / 128), 256, 0, stream>>>(ATT, Ob, out, M_ROWS, EMB, EMB);
}